// Round 13
// baseline (370.088 us; speedup 1.0000x reference)
//
#include <hip/hip_runtime.h>
#include <hip/hip_bf16.h>
#include <math.h>

// Problem constants
#define Ln     35
#define CINn   21
#define CINP   24        // padded CIN (multiple of 8 -> aligned b128 im2col reads)
#define Fn     128
#define Kn     9
#define Hn     64
#define GB     16        // batch rows per block
#define SEQ_STRIDE 1064  // 44 rows*24 + 8 slack (shorts); l=35 window ends exactly at 1064
#define TILE_STRIDE 136  // 128 + 8 pad (shorts)
#define YP_STRIDE 136    // floats per l-row in s_yp: 8 waves*16 batch + 8 pad
#define NYL    16        // s_yp rows: l in [10,25] only

typedef __attribute__((ext_vector_type(8))) short short8;
typedef __attribute__((ext_vector_type(4))) float f32x4;

static __device__ __forceinline__ unsigned short bf16bits(float f) {
    __hip_bfloat16 h = __float2bfloat16(f);
    return *(unsigned short*)&h;
}

// f32 lane-row (16-lane) sum via DPP rotate-accumulate: VALU pipe, zero LDS traffic.
template <int CTRL>
static __device__ __forceinline__ float dpp_add(float v) {
    int r = __builtin_amdgcn_update_dpp(0, __builtin_bit_cast(int, v),
                                        CTRL, 0xF, 0xF, true);
    return v + __builtin_bit_cast(float, r);
}
static __device__ __forceinline__ float row_sum16(float v) {
    v = dpp_add<0x128>(v);   // ror 8
    v = dpp_add<0x124>(v);   // ror 4
    v = dpp_add<0x122>(v);   // ror 2
    v = dpp_add<0x121>(v);   // ror 1
    return v;
}

// ---------------- single fused kernel: 16 batch rows / block, 512 threads ----------------
// 8 waves/block; wave w owns conv f-tile [16w,16w+16) and MLP n-tile [16w,16w+16)
// (n<64 = n-head, n>=64 = c-head). Weight frags per wave: 28+16 = 44 VGPRs.
// STRUCTURE RULES (rounds 1-12, final form):
//  * Occupancy is REGISTER-bound at the 128 unified regs/wave cap (2 blocks/CU, ~42%
//    at any LDS size). Every register-restructuring attempt spilled (r1-4,r6,r7,r11).
//    Only register-neutral, shape-preserving edits land.
//  * Uniform 18-stage loop, explicit af0[7]/af1[7] arrays, block-uniform guards with
//    no conditionally-defined values escaping. Gate every edit on WRITE_SIZE==128KiB.
//  * Conv b128 bank pattern is at the wave64 floor; don't swizzle.
// Round-13 deltas (register-shape-neutral):
//  * 8-slot tile ring + 2-stage-LAGGED MLP: stage l0 writes tiles(l0,l1) to slots
//    l&7; MLP at stage l0 consumes tiles(l0-4,l0-3). Barriers only at l0 in
//    {12,16,20,24} -> 4 in-loop barriers (was 8), and every tile read is >=2 stages
//    downstream of its write (publish latency off the critical path).
//    Ring proof: writes@{10..24}, reads@{14..28}; slot reuse distance = 4 stages;
//    every write->read and read->rewrite pair has an intervening barrier.
//  * Bias folded into accumulator init (cacc=cbias, hacc=b1v): -16 v_add/stage/wave.
//  * sum_n guards merged (l1<10 iff l0<10, l0 even); cm via unsigned range compare.
//  * LDS 60.4 -> 77.6 KB (2 blocks = 155 KB < 160 KB; residency reg-bound anyway).
__global__ __launch_bounds__(512, 4) void fused_kernel(
    const float* __restrict__ seq,    const int*   __restrict__ plen_arr,
    const float* __restrict__ conv_w, const float* __restrict__ conv_b,
    const float* __restrict__ n_w1,   const float* __restrict__ n_b1,
    const float* __restrict__ n_w2,   const float* __restrict__ n_b2,
    const float* __restrict__ c_w1,   const float* __restrict__ c_b1,
    const float* __restrict__ c_w2,   const float* __restrict__ c_b2,
    const float* __restrict__ navg_w, const float* __restrict__ navg_b,
    const float* __restrict__ cavg_w, const float* __restrict__ cavg_b,
    const float* __restrict__ out_w,  const float* __restrict__ out_b,
    float* __restrict__ out)
{
    __shared__ __align__(16) unsigned short s_seq[GB * SEQ_STRIDE];      // 34048 B
    __shared__ __align__(16) unsigned short s_tile[8][GB * TILE_STRIDE]; // 34816 B
    __shared__ __align__(16) float s_yp[NYL * YP_STRIDE];                //  8704 B: [l-10][wave*16+m]
    // overlays on s_seq (dead after the main loop):
    float* s_y   = (float*)s_seq;            // [2][GB][36] = 1152 floats
    float* s_avg = (float*)s_seq + 1152;     // [8 waves][2][GB] = 256 floats

    const int t    = threadIdx.x;
    const int wave = t >> 6;                 // 0..7
    const int lane = t & 63;
    const int quad = lane >> 4;
    const int col  = lane & 15;
    const int b0   = blockIdx.x * GB;

    // ---- zero-init padded seq (pad rows/channels + slack must be 0) ----
    {
        uint4* p = (uint4*)s_seq;            // 34048/16 = 2128 uint4
        for (int i = t; i < (GB * SEQ_STRIDE) / 8; i += 512)
            p[i] = make_uint4(0u, 0u, 0u, 0u);
    }

    // ---- per-lane loop-invariant weight fragments (single tile per wave) ----
    // conv A-frag (operand-swapped): A[m=f=16*wave+col][k=kk], kk = k*24+c
    // MLP  B-frag: B[k=f][n=16*wave+col]
    short8 wb[7];
    short8 w1b[4];
    float  cbias[4], b1v, w2v;
    const int head = wave >> 2;              // 0 = n-head (waves 0-3), 1 = c (waves 4-7)
    {
        const int ng = wave * 16 + col;      // conv f (A m-index) AND mlp n-index
        #pragma unroll
        for (int s = 0; s < 7; s++) {
            short8 v;
            #pragma unroll
            for (int j = 0; j < 8; j++) {
                int kk = 32 * s + quad * 8 + j;
                int k = kk / CINP, c = kk % CINP;
                float f = (k < Kn && c < CINn) ? conv_w[(k * CINn + c) * Fn + ng] : 0.0f;
                v[j] = (short)bf16bits(f);
            }
            wb[s] = v;
        }
        const int nl = ng & 63;
        #pragma unroll
        for (int s = 0; s < 4; s++) {
            short8 v;
            #pragma unroll
            for (int j = 0; j < 8; j++) {
                int k = 32 * s + quad * 8 + j;
                float f = head ? c_w1[k * Hn + nl] : n_w1[k * Hn + nl];
                v[j] = (short)bf16bits(f);
            }
            w1b[s] = v;
        }
        #pragma unroll
        for (int r = 0; r < 4; r++)
            cbias[r] = conv_b[wave * 16 + 4 * quad + r];
        b1v = head ? c_b1[nl] : n_b1[nl];
        w2v = head ? c_w2[nl] : n_w2[nl];
    }
    const int plen_lane = plen_arr[b0 + col];   // this lane's batch (=col) plen

    __syncthreads();   // zero-init done before data fill

    // ---- stage seq -> bf16 LDS, rows shifted +4 (SAME pad), c<21 only ----
    // float4 global loads; element (bi,l,c) -> bi*1064 + (4+l)*24 + c. For a float4
    // at r = l*21+c, element j: row wrap (+3), batch wrap (+224 more). (r10-verified)
    {
        const float4* gsrc = (const float4*)(seq + (size_t)b0 * (Ln * CINn));
        for (int i = t; i < (GB * Ln * CINn) / 4; i += 512) {
            int i4 = i * 4;
            int bi = i4 / (Ln * CINn), r = i4 - bi * (Ln * CINn);
            int l = r / CINn, c = r - l * CINn;
            float4 v = gsrc[i];
            int base = bi * SEQ_STRIDE + (4 + l) * CINP + c;
            #pragma unroll
            for (int j = 0; j < 4; j++) {
                float fj = (j == 0) ? v.x : (j == 1) ? v.y : (j == 2) ? v.z : v.w;
                int adj = ((c + j >= CINn) ? 3 : 0) + ((r + j >= Ln * CINn) ? 224 : 0);
                s_seq[base + j + adj] = bf16bits(fj);
            }
        }
    }
    __syncthreads();

    float sum_n[4] = {0.f,0.f,0.f,0.f};
    float sum_c[4] = {0.f,0.f,0.f,0.f};

    // ---- main loop: 2 l per stage, 18 stages. Tile writes @ l0 in [10,26) into
    // slots l&7; lagged MLP @ l0 in [14,30) consumes tiles(l0-4,l0-3); barriers
    // only @ l0 in {12,16,20,24}. l=35 is a computed pad column (auto-masked).
    for (int l0 = 0; l0 < 36; l0 += 2) {
        const int l1 = l0 + 1;
        // ---- conv GEMM (operand-swapped): D^T[f][batch], wave's 16-f tile ----
        short8 af0[7], af1[7];
        #pragma unroll
        for (int s = 0; s < 7; s++) {
            af0[s] = *(const short8*)&s_seq[col * SEQ_STRIDE + l0 * CINP + 32 * s + quad * 8];
            af1[s] = *(const short8*)&s_seq[col * SEQ_STRIDE + l1 * CINP + 32 * s + quad * 8];
        }
        f32x4 cacc0 = {cbias[0], cbias[1], cbias[2], cbias[3]};   // bias pre-folded
        f32x4 cacc1 = {cbias[0], cbias[1], cbias[2], cbias[3]};
        #pragma unroll
        for (int s = 0; s < 7; s++) {
            cacc0 = __builtin_amdgcn_mfma_f32_16x16x32_bf16(wb[s], af0[s], cacc0, 0, 0, 0);
            cacc1 = __builtin_amdgcn_mfma_f32_16x16x32_bf16(wb[s], af1[s], cacc1, 0, 0, 0);
        }
        // ---- epilogue: lane holds batch=col, f = 16*wave + 4q + r ----
        float a0 = fmaxf(cacc0[0], 0.0f);
        float a1 = fmaxf(cacc0[1], 0.0f);
        float a2 = fmaxf(cacc0[2], 0.0f);
        float a3 = fmaxf(cacc0[3], 0.0f);
        float e0 = fmaxf(cacc1[0], 0.0f);
        float e1 = fmaxf(cacc1[1], 0.0f);
        float e2 = fmaxf(cacc1[2], 0.0f);
        float e3 = fmaxf(cacc1[3], 0.0f);
        if (l0 < 10) {            // wave-uniform; l1<10 iff l0<10 (l0 even)
            sum_n[0] += a0 + e0; sum_n[1] += a1 + e1;
            sum_n[2] += a2 + e2; sum_n[3] += a3 + e3;
        }
        {
            // cm = 1 iff 10+plen <= l < 20+plen, via single unsigned range compare
            float cm0 = ((unsigned)(l0 - 10 - plen_lane) < 10u) ? 1.0f : 0.0f;
            float cm1 = ((unsigned)(l1 - 10 - plen_lane) < 10u) ? 1.0f : 0.0f;
            sum_c[0] += cm0 * a0 + cm1 * e0;
            sum_c[1] += cm0 * a1 + cm1 * e1;
            sum_c[2] += cm0 * a2 + cm1 * e2;
            sum_c[3] += cm0 * a3 + cm1 * e3;
        }

        // ---- tile publish: only l whose y is consumed (l in [10,25]) ----
        if (l0 >= 10 && l0 < 26) {           // block-uniform
            ushort4 pk0 = { bf16bits(a0), bf16bits(a1), bf16bits(a2), bf16bits(a3) };
            ushort4 pk1 = { bf16bits(e0), bf16bits(e1), bf16bits(e2), bf16bits(e3) };
            *(ushort4*)&s_tile[l0 & 7][col * TILE_STRIDE + wave * 16 + 4 * quad] = pk0;
            *(ushort4*)&s_tile[l1 & 7][col * TILE_STRIDE + wave * 16 + 4 * quad] = pk1;
        }

        // ---- lagged MLP: consume tiles(l0-4, l0-3), published >=1 barrier ago ----
        if (l0 >= 14 && l0 < 30) {           // block-uniform; lp in [10,25]
            const int lp0 = l0 - 4, lp1 = l0 - 3;
            short8 am0[4], am1[4];
            #pragma unroll
            for (int s = 0; s < 4; s++) {
                am0[s] = *(const short8*)&s_tile[lp0 & 7][col * TILE_STRIDE + 32 * s + quad * 8];
                am1[s] = *(const short8*)&s_tile[lp1 & 7][col * TILE_STRIDE + 32 * s + quad * 8];
            }
            f32x4 hacc0 = {b1v, b1v, b1v, b1v};   // bias pre-folded
            f32x4 hacc1 = {b1v, b1v, b1v, b1v};
            #pragma unroll
            for (int s = 0; s < 4; s++) {
                hacc0 = __builtin_amdgcn_mfma_f32_16x16x32_bf16(am0[s], w1b[s], hacc0, 0, 0, 0);
                hacc1 = __builtin_amdgcn_mfma_f32_16x16x32_bf16(am1[s], w1b[s], hacc1, 0, 0, 0);
            }
            // ---- y partial = relu(h) @ w2 over this wave's 16 n; DPP row-sum ----
            float p0[4], p1[4];
            #pragma unroll
            for (int r = 0; r < 4; r++) {
                p0[r] = row_sum16(fmaxf(hacc0[r], 0.f) * w2v);
                p1[r] = row_sum16(fmaxf(hacc1[r], 0.f) * w2v);
            }
            if (col == 0) {                  // batch index = 4*quad + r
                *(f32x4*)&s_yp[(lp0 - 10) * YP_STRIDE + wave * 16 + quad * 4] =
                    (f32x4){p0[0], p0[1], p0[2], p0[3]};
                *(f32x4*)&s_yp[(lp1 - 10) * YP_STRIDE + wave * 16 + quad * 4] =
                    (f32x4){p1[0], p1[1], p1[2], p1[3]};
            }
        }

        // ---- barrier cadence: every other write-stage publishes 4 l's at once ----
        if (l0 >= 12 && l0 <= 24 && (l0 & 3) == 0)   // l0 in {12,16,20,24}
            __syncthreads();
    }
    __syncthreads();   // all s_seq reads + stage-26/28 s_yp writes done -> overlay safe

    // ---- flank-average partials: apply navg_w/cavg_w post-loop ----
    {
        float an = 0.f, ac = 0.f;
        #pragma unroll
        for (int r = 0; r < 4; r++) {
            int fidx = wave * 16 + 4 * quad + r;
            an += sum_n[r] * navg_w[fidx];
            ac += sum_c[r] * cavg_w[fidx];
        }
        an += __shfl_xor(an, 16); an += __shfl_xor(an, 32);   // sum over quads
        ac += __shfl_xor(ac, 16); ac += __shfl_xor(ac, 32);
        if (quad == 0) {                     // lane < 16: one per batch
            s_avg[wave * 2 * GB + 0 * GB + col] = an;
            s_avg[wave * 2 * GB + 1 * GB + col] = ac;
        }
    }
    __syncthreads();

    // ---- y finalize: y = tanh(sum of 4 wave-partials + b2), l in [10,25] (512 vals) ----
    // m-fastest decomposition: 64 lanes cover all 32 banks 2-way (conflict-free);
    // YP_STRIDE=136 decorrelates the per-l bank offset (136%32 = 8).
    {
        const float bn = n_b2[0], bc = c_b2[0];
        for (int i = t; i < 2 * GB * NYL; i += 512) {
            int m = i & 15, rem = i >> 4;        // rem = 0..31
            int li = rem & 15, hd = rem >> 4;    // li = l-10
            float v = (hd ? bc : bn);
            #pragma unroll
            for (int w = 0; w < 4; w++)
                v += s_yp[li * YP_STRIDE + (hd * 4 + w) * 16 + m];
            s_y[hd * GB * 36 + m * 36 + (10 + li)] = tanhf(v);
        }
    }
    __syncthreads();

    // ---- final combine: one thread per batch row ----
    if (t < GB) {
        const int m = t;
        const int plen = plen_arr[b0 + m];
        const float* ym = s_y + m * 36;               // n-head row
        const float* yc = s_y + GB * 36 + m * 36;     // c-head row
        float cleaved_n = ym[10];
        float mn = 0.f;   // reference maxes (y+1)*mask over ALL l; unmasked give 0
        for (int l = 11; l < 10 + plen; l++) mn = fmaxf(mn, ym[l] + 1.f);
        float maxpool_n = -(mn - 1.f);
        float cleaved_c = yc[10 + plen - 1];
        float mc = 0.f;
        for (int l = 10; l < 10 + plen - 1; l++) mc = fmaxf(mc, yc[l] + 1.f);
        float maxpool_c = -(mc - 1.f);
        float sn = 0.f, sc = 0.f;
        #pragma unroll
        for (int w = 0; w < 8; w++) {
            sn += s_avg[w * 2 * GB + 0 * GB + m];
            sc += s_avg[w * 2 * GB + 1 * GB + m];
        }
        float avg_n = tanhf(sn * 0.1f + navg_b[0]);
        float avg_c = tanhf(sc * 0.1f + cavg_b[0]);
        float comb = cleaved_n * out_w[0] + maxpool_n * out_w[1] + avg_n * out_w[2]
                   + cleaved_c * out_w[3] + maxpool_c * out_w[4] + avg_c * out_w[5]
                   + out_b[0];
        out[b0 + m] = 1.f / (1.f + expf(-comb));
    }
}

extern "C" void kernel_launch(void* const* d_in, const int* in_sizes, int n_in,
                              void* d_out, int out_size, void* d_ws, size_t ws_size,
                              hipStream_t stream) {
    const int B = in_sizes[1];
    fused_kernel<<<B / GB, 512, 0, stream>>>(
        (const float*)d_in[0],  (const int*)d_in[1],
        (const float*)d_in[2],  (const float*)d_in[3],
        (const float*)d_in[4],  (const float*)d_in[5],
        (const float*)d_in[6],  (const float*)d_in[7],
        (const float*)d_in[8],  (const float*)d_in[9],
        (const float*)d_in[10], (const float*)d_in[11],
        (const float*)d_in[12], (const float*)d_in[13],
        (const float*)d_in[14], (const float*)d_in[15],
        (const float*)d_in[16], (const float*)d_in[17],
        (float*)d_out);
}